// Round 6
// baseline (656.554 us; speedup 1.0000x reference)
//
#include <hip/hip_runtime.h>
#include <hip/hip_fp16.h>
#include <hip/hip_cooperative_groups.h>
#include <math.h>

namespace cg = cooperative_groups;

#define N_NODES 100000
#define N_EDGES 3200000
#define EPRIME  (N_EDGES + N_NODES)
#define NFEAT   512
#define HID     16
#define NCLS    10

#define NPB     256                           // nodes per bucket
#define NB      ((N_NODES + NPB - 1) / NPB)   // 391 buckets
#define CHUNK   4096                          // edges per partition chunk
#define NCHUNKS ((EPRIME + CHUNK - 1) / CHUNK)  // 806
#define CAPB    10240                         // slot capacity per bucket (mean 8448 + 19 sigma)
#define GRID2   768                           // coop grid: 3/CU needed, 4/CU guaranteed

union U2 { unsigned int u; __half2 h; };
__device__ __forceinline__ float2 u2f(unsigned int v) {
  U2 t; t.u = v; return __half22float2(t.h);
}

// ---------------------------------------------------------------------------
// D1: hn1 = fp16(normalize(relu(x @ W1 + b1))); norms1 = ||relu||.
// One wave per row; W1 (512x16) in registers; prefetch depth 2.
// Block 0 also zeroes gcur (consumed by the next dispatch).
// ---------------------------------------------------------------------------
__global__ __launch_bounds__(256) void k_gemm_norm(const float* __restrict__ x,
                                                   const float* __restrict__ W1,
                                                   const float* __restrict__ b1,
                                                   __half* __restrict__ hn1,
                                                   float* __restrict__ norms1,
                                                   int* __restrict__ gcur) {
  if (blockIdx.x == 0)
    for (int i = threadIdx.x; i < NB; i += 256) gcur[i] = 0;

  const int lane = threadIdx.x & 63;
  const int wid  = blockIdx.x * 4 + (threadIdx.x >> 6);
  const int nw   = gridDim.x * 4;

  float4 w[8][4];
#pragma unroll
  for (int kk = 0; kk < 8; ++kk)
#pragma unroll
    for (int j = 0; j < 4; ++j)
      w[kk][j] = *reinterpret_cast<const float4*>(W1 + (lane * 8 + kk) * 16 + j * 4);

  const int outCol = (lane >> 2) & 15;
  const float bias = b1[outCol];

  const float4 z4 = make_float4(0.f, 0.f, 0.f, 0.f);
  float4 c0 = z4, c1 = z4, p0 = z4, p1 = z4, t0 = z4, t1 = z4;

  if (wid < N_NODES) {
    c0 = *reinterpret_cast<const float4*>(x + (size_t)wid * NFEAT + lane * 8);
    c1 = *reinterpret_cast<const float4*>(x + (size_t)wid * NFEAT + lane * 8 + 4);
  }
  if (wid + nw < N_NODES) {
    p0 = *reinterpret_cast<const float4*>(x + (size_t)(wid + nw) * NFEAT + lane * 8);
    p1 = *reinterpret_cast<const float4*>(x + (size_t)(wid + nw) * NFEAT + lane * 8 + 4);
  }

  for (int row = wid; row < N_NODES; row += nw) {
    const int r2 = row + 2 * nw;
    if (r2 < N_NODES) {
      t0 = *reinterpret_cast<const float4*>(x + (size_t)r2 * NFEAT + lane * 8);
      t1 = *reinterpret_cast<const float4*>(x + (size_t)r2 * NFEAT + lane * 8 + 4);
    }

    float xs[8] = {c0.x, c0.y, c0.z, c0.w, c1.x, c1.y, c1.z, c1.w};

    float acc[16];
#pragma unroll
    for (int j = 0; j < 16; ++j) acc[j] = 0.f;

#pragma unroll
    for (int kk = 0; kk < 8; ++kk) {
      const float xv = xs[kk];
#pragma unroll
      for (int j4 = 0; j4 < 4; ++j4) {
        acc[j4 * 4 + 0] = fmaf(xv, w[kk][j4].x, acc[j4 * 4 + 0]);
        acc[j4 * 4 + 1] = fmaf(xv, w[kk][j4].y, acc[j4 * 4 + 1]);
        acc[j4 * 4 + 2] = fmaf(xv, w[kk][j4].z, acc[j4 * 4 + 2]);
        acc[j4 * 4 + 3] = fmaf(xv, w[kk][j4].w, acc[j4 * 4 + 3]);
      }
    }

#pragma unroll
    for (int i = 0; i < 8; ++i) {
      float send = (lane & 32) ? acc[i] : acc[i + 8];
      float r = __shfl_xor(send, 32);
      acc[i] = ((lane & 32) ? acc[i + 8] : acc[i]) + r;
    }
#pragma unroll
    for (int i = 0; i < 4; ++i) {
      float send = (lane & 16) ? acc[i] : acc[i + 4];
      float r = __shfl_xor(send, 16);
      acc[i] = ((lane & 16) ? acc[i + 4] : acc[i]) + r;
    }
#pragma unroll
    for (int i = 0; i < 2; ++i) {
      float send = (lane & 8) ? acc[i] : acc[i + 2];
      float r = __shfl_xor(send, 8);
      acc[i] = ((lane & 8) ? acc[i + 2] : acc[i]) + r;
    }
    {
      float send = (lane & 4) ? acc[0] : acc[1];
      float r = __shfl_xor(send, 4);
      acc[0] = ((lane & 4) ? acc[1] : acc[0]) + r;
    }
    acc[0] += __shfl_xor(acc[0], 2);
    acc[0] += __shfl_xor(acc[0], 1);

    const float v = fmaxf(acc[0] + bias, 0.f);
    float ss = v * v;
    ss += __shfl_xor(ss, 4);
    ss += __shfl_xor(ss, 8);
    ss += __shfl_xor(ss, 16);
    ss += __shfl_xor(ss, 32);
    const float nrm = sqrtf(ss);
    const float vs = v / fmaxf(nrm, 1e-12f);

    const float wv = __shfl(vs, (lane & 15) * 4);
    if (lane < 16) hn1[(size_t)row * HID + lane] = __float2half_rn(wv);
    if (lane == 0) norms1[row] = nrm;

    c0 = p0; c1 = p1; p0 = t0; p1 = t1;
  }
}

// ---------------------------------------------------------------------------
// Partition one 4096-edge chunk into per-bucket packed slot areas
// (src | local_dst << 20).  Safe to call in a per-block loop.
// ---------------------------------------------------------------------------
__device__ void part_chunk(int c, const int* __restrict__ ei,
                           int* __restrict__ gcur,
                           unsigned int* __restrict__ slots) {
  __shared__ int sh_hist[NB];
  __shared__ int sh_gbase[NB];
  const int tid = threadIdx.x;

  for (int i = tid; i < NB; i += 256) sh_hist[i] = 0;
  __syncthreads();

  const int base = c * CHUNK;
  unsigned int pk[CHUNK / 256];
  int bk[CHUNK / 256];
  int rk[CHUNK / 256];
#pragma unroll
  for (int j = 0; j < CHUNK / 256; ++j) {
    int e = base + j * 256 + tid;
    bool valid = (e < EPRIME);
    int srcv = 0, d = 0;
    if (valid) {
      if (e < N_EDGES) { srcv = ei[e]; d = ei[N_EDGES + e]; }
      else             { srcv = d = e - N_EDGES; }
    }
    bk[j] = valid ? (d >> 8) : -1;
    pk[j] = (unsigned)srcv | ((unsigned)(d & 255) << 20);
    rk[j] = valid ? atomicAdd(&sh_hist[d >> 8], 1) : 0;
  }
  __syncthreads();

  for (int i = tid; i < NB; i += 256) {
    int hc = sh_hist[i];
    sh_gbase[i] = hc ? atomicAdd(&gcur[i], hc) : 0;
  }
  __syncthreads();

#pragma unroll
  for (int j = 0; j < CHUNK / 256; ++j)
    if (bk[j] >= 0)
      slots[(size_t)bk[j] * CAPB + sh_gbase[bk[j]] + rk[j]] = pk[j];
}

// ---------------------------------------------------------------------------
// Per-bucket CSR finalize for bucket `bid` (bid == NB does pads).
// Redundant prefix over bucket counts replaces a separate scan kernel.
// ---------------------------------------------------------------------------
__device__ void csr_finalize(int bid, const unsigned int* __restrict__ slots,
                             const int* __restrict__ gcur,
                             int* __restrict__ offs, int* __restrict__ csr) {
  const int tid = threadIdx.x;
  if (bid == NB) {
    if (tid == 0) offs[N_NODES] = EPRIME;
    if (tid < 16) csr[EPRIME + tid] = 0;  // pad for pull over-read
    return;
  }

  __shared__ int sh_cnt[NPB];
  __shared__ int sh_cnt2[NPB];
  __shared__ int sh_sc[NPB];
  __shared__ int sh_loffs[NPB];
  __shared__ int sh_w[4];

  int partial = 0;
  for (int i = tid; i < bid; i += 256) partial += gcur[i];
#pragma unroll
  for (int m = 1; m < 64; m <<= 1) partial += __shfl_xor(partial, m);
  if ((tid & 63) == 0) sh_w[tid >> 6] = partial;
  sh_cnt[tid] = 0;
  sh_cnt2[tid] = 0;
  __syncthreads();

  const int base = sh_w[0] + sh_w[1] + sh_w[2] + sh_w[3];
  const int ne = gcur[bid];
  const unsigned int* my = slots + (size_t)bid * CAPB;

  for (int i = tid; i < ne; i += 256) atomicAdd(&sh_cnt[my[i] >> 20], 1);
  __syncthreads();

  int v = sh_cnt[tid];
  sh_sc[tid] = v;
  __syncthreads();
  for (int d = 1; d < NPB; d <<= 1) {
    int u = (tid >= d) ? sh_sc[tid - d] : 0;
    __syncthreads();
    sh_sc[tid] += u;
    __syncthreads();
  }
  const int excl = sh_sc[tid] - v;
  sh_loffs[tid] = excl;

  const int node = bid * NPB + tid;
  if (node < N_NODES) offs[node] = base + excl;
  __syncthreads();

  // direct scatter within this bucket's ~33KB csr region (L2-local)
  for (int i = tid; i < ne; i += 256) {
    unsigned p = my[i];
    int local = p >> 20;
    int r = atomicAdd(&sh_cnt2[local], 1);
    csr[base + sh_loffs[local] + r] = (int)(p & 0xFFFFF);
  }
}

// ---------------------------------------------------------------------------
// Pull-mode AGNN conv body, one wave per dst node (wid0, stride given).
// 16 edge slots x 4 feature lanes; hn fp16 (L2-resident), fp32 accumulate.
// FINAL=false: fuse next layer's normalize.  FINAL=true: fuse logits +
// log_softmax.  Lane (slot s, quad q) holds only W2 col s / rows 4q..4q+3.
// ---------------------------------------------------------------------------
template <bool FINAL>
__device__ __forceinline__ void pull_body(const __half* __restrict__ hn,
                                          const float* __restrict__ norms,
                                          const int* __restrict__ offs,
                                          const int* __restrict__ csr,
                                          float beta,
                                          __half* __restrict__ out_hn,
                                          float* __restrict__ out_norms,
                                          const float* __restrict__ W2,
                                          const float* __restrict__ b2,
                                          float* __restrict__ out,
                                          int wid0, int stride) {
  const int lane = threadIdx.x & 63;
  const int q    = lane & 3;   // feature quad
  const int slot = lane >> 2;  // edge slot 0..15

  float w4x = 0.f, w4y = 0.f, w4z = 0.f, w4w = 0.f, b2v = 0.f;
  if (FINAL) {
    const int sc = (slot < NCLS) ? slot : 0;
    w4x = W2[(q * 4 + 0) * NCLS + sc];
    w4y = W2[(q * 4 + 1) * NCLS + sc];
    w4z = W2[(q * 4 + 2) * NCLS + sc];
    w4w = W2[(q * 4 + 3) * NCLS + sc];
    b2v = b2[sc];
  }

  for (int node = wid0; node < N_NODES; node += stride) {
    const uint2 qraw = *reinterpret_cast<const uint2*>(hn + (size_t)node * HID + q * 4);
    const float2 qa = u2f(qraw.x), qb = u2f(qraw.y);
    const int s = offs[node], e = offs[node + 1];

    float den = 0.f;
    float ax = 0.f, ay = 0.f, az = 0.f, aw = 0.f;

    for (int bi = s; bi < e; bi += 16) {
      const int i = bi + slot;
      const int src = csr[i];  // over-read covered by zero pad
      const uint2 r = *reinterpret_cast<const uint2*>(hn + (size_t)src * HID + q * 4);
      const float2 f0 = u2f(r.x), f1 = u2f(r.y);
      float pd = qa.x * f0.x + qa.y * f0.y + qb.x * f1.x + qb.y * f1.y;
      pd += __shfl_xor(pd, 1);
      pd += __shfl_xor(pd, 2);
      const float t = (i < e) ? __expf(beta * pd) : 0.f;
      den += t;
      const float wgt = t * norms[src];
      ax += wgt * f0.x; ay += wgt * f0.y; az += wgt * f1.x; aw += wgt * f1.y;
    }

#pragma unroll
    for (int m = 4; m <= 32; m <<= 1) {
      den += __shfl_xor(den, m);
      ax  += __shfl_xor(ax, m);
      ay  += __shfl_xor(ay, m);
      az  += __shfl_xor(az, m);
      aw  += __shfl_xor(aw, m);
    }
    const float inv = 1.0f / den;  // self-loop guarantees den > 0
    ax *= inv; ay *= inv; az *= inv; aw *= inv;

    if (!FINAL) {
      float ssn = ax * ax + ay * ay + az * az + aw * aw;
      ssn += __shfl_xor(ssn, 1);
      ssn += __shfl_xor(ssn, 2);
      const float nrm = sqrtf(ssn);
      const float ninv = 1.0f / fmaxf(nrm, 1e-12f);
      if (lane < 4) {
        U2 lo, hi;
        lo.h = __floats2half2_rn(ax * ninv, ay * ninv);
        hi.h = __floats2half2_rn(az * ninv, aw * ninv);
        *reinterpret_cast<uint2*>(out_hn + (size_t)node * HID + q * 4) =
            make_uint2(lo.u, hi.u);
        if (lane == 0) out_norms[node] = nrm;
      }
    } else {
      // partial logit for class `slot` over this lane's 4 features
      float part = ax * w4x + ay * w4y + az * w4z + aw * w4w;
      part += __shfl_xor(part, 1);
      part += __shfl_xor(part, 2);
      const float logit = part + b2v;  // valid on slots 0..9 (all q replicate)

      float lg[NCLS];
#pragma unroll
      for (int c = 0; c < NCLS; ++c) lg[c] = __shfl(logit, c * 4);
      float m = lg[0];
#pragma unroll
      for (int c = 1; c < NCLS; ++c) m = fmaxf(m, lg[c]);
      float se = 0.f;
#pragma unroll
      for (int c = 0; c < NCLS; ++c) se += __expf(lg[c] - m);
      const float ls = m + logf(se);

      const float myv = __shfl(logit, lane * 4);  // per-lane shuffle, no reg-array index
      if (lane < NCLS) out[(size_t)node * NCLS + lane] = myv - ls;
    }
  }
}

// ---------------------------------------------------------------------------
// D2 (cooperative): part / csr / pull1 / pull2+out with grid syncs.
// ---------------------------------------------------------------------------
__global__ __launch_bounds__(256, 4) void k_mega(const int* __restrict__ ei,
                                                 const float* __restrict__ beta_ptr,
                                                 const __half* __restrict__ hn1,
                                                 const float* __restrict__ norms1,
                                                 __half* __restrict__ hn2,
                                                 float* __restrict__ norms2,
                                                 int* __restrict__ gcur,
                                                 int* __restrict__ offs,
                                                 int* __restrict__ csr,
                                                 unsigned int* __restrict__ slots,
                                                 const float* __restrict__ W2,
                                                 const float* __restrict__ b2,
                                                 float* __restrict__ out) {
  cg::grid_group grid = cg::this_grid();
  const int bid  = blockIdx.x;
  const int wid0 = bid * 4 + (threadIdx.x >> 6);

  for (int c = bid; c < NCHUNKS; c += GRID2)
    part_chunk(c, ei, gcur, slots);
  grid.sync();

  if (bid <= NB)
    csr_finalize(bid, slots, gcur, offs, csr);
  grid.sync();

  pull_body<false>(hn1, norms1, offs, csr, 1.0f, hn2, norms2,
                   nullptr, nullptr, nullptr, wid0, GRID2 * 4);
  grid.sync();

  pull_body<true>(hn2, norms2, offs, csr, beta_ptr[0], nullptr, nullptr,
                  W2, b2, out, wid0, GRID2 * 4);
}

// ---------------------------------------------------------------------------
// Fallback path: same device bodies as regular kernels.
// ---------------------------------------------------------------------------
__global__ __launch_bounds__(256) void k_part(const int* __restrict__ ei,
                                              int* __restrict__ gcur,
                                              unsigned int* __restrict__ slots) {
  part_chunk(blockIdx.x, ei, gcur, slots);
}

__global__ __launch_bounds__(256) void k_csrfin(const unsigned int* __restrict__ slots,
                                                const int* __restrict__ gcur,
                                                int* __restrict__ offs,
                                                int* __restrict__ csr) {
  csr_finalize(blockIdx.x, slots, gcur, offs, csr);
}

__global__ __launch_bounds__(256) void k_pull1(const __half* __restrict__ hn1,
                                               const float* __restrict__ norms1,
                                               const int* __restrict__ offs,
                                               const int* __restrict__ csr,
                                               __half* __restrict__ hn2,
                                               float* __restrict__ norms2) {
  pull_body<false>(hn1, norms1, offs, csr, 1.0f, hn2, norms2,
                   nullptr, nullptr, nullptr,
                   blockIdx.x * 4 + (threadIdx.x >> 6), gridDim.x * 4);
}

__global__ __launch_bounds__(256) void k_pull2(const __half* __restrict__ hn2,
                                               const float* __restrict__ norms2,
                                               const int* __restrict__ offs,
                                               const int* __restrict__ csr,
                                               const float* __restrict__ beta_ptr,
                                               const float* __restrict__ W2,
                                               const float* __restrict__ b2,
                                               float* __restrict__ out) {
  pull_body<true>(hn2, norms2, offs, csr, beta_ptr[0], nullptr, nullptr,
                  W2, b2, out, blockIdx.x * 4 + (threadIdx.x >> 6), gridDim.x * 4);
}

// ---------------------------------------------------------------------------
extern "C" void kernel_launch(void* const* d_in, const int* in_sizes, int n_in,
                              void* d_out, int out_size, void* d_ws, size_t ws_size,
                              hipStream_t stream) {
  const float* x    = (const float*)d_in[0];
  const int*   ei   = (const int*)d_in[1];
  const float* W1   = (const float*)d_in[2];
  const float* b1   = (const float*)d_in[3];
  const float* beta = (const float*)d_in[4];
  const float* W2   = (const float*)d_in[5];
  const float* b2   = (const float*)d_in[6];
  float* out = (float*)d_out;

  // Workspace layout (~37 MB); 16B alignment by construction.
  float*  base   = (float*)d_ws;
  __half* hn1    = (__half*)base;                          // N*16 half
  float*  norms1 = base + (size_t)N_NODES * 8;             // N
  __half* hn2    = (__half*)(norms1 + N_NODES);            // N*16 half
  float*  norms2 = (float*)(hn2 + (size_t)N_NODES * HID);  // N
  int*    offs   = (int*)(norms2 + N_NODES);               // N+1 (+pad)
  int*    gcur   = offs + N_NODES + 8;                     // NB
  int*    csr    = gcur + NB + 1;                          // EPRIME + 16 pad
  unsigned int* slots = (unsigned int*)(csr + EPRIME + 16);  // NB*CAPB

  k_gemm_norm<<<1024, 256, 0, stream>>>(x, W1, b1, hn1, norms1, gcur);

  // Cooperative path with occupancy guard + error fallback.
  int maxB = 0;
  hipError_t oe = hipOccupancyMaxActiveBlocksPerMultiprocessor(&maxB, k_mega, 256, 0);
  bool coop = (oe == hipSuccess) && (maxB * 256 >= GRID2);  // 256 CUs on MI355X

  if (coop) {
    void* args[] = {(void*)&ei, (void*)&beta, (void*)&hn1, (void*)&norms1,
                    (void*)&hn2, (void*)&norms2, (void*)&gcur, (void*)&offs,
                    (void*)&csr, (void*)&slots, (void*)&W2, (void*)&b2,
                    (void*)&out};
    hipError_t le = hipLaunchCooperativeKernel((void*)k_mega, dim3(GRID2),
                                               dim3(256), args, 0, stream);
    if (le != hipSuccess) { (void)hipGetLastError(); coop = false; }
  }

  if (!coop) {
    k_part<<<NCHUNKS, 256, 0, stream>>>(ei, gcur, slots);
    k_csrfin<<<NB + 1, 256, 0, stream>>>(slots, gcur, offs, csr);
    k_pull1<<<6250, 256, 0, stream>>>(hn1, norms1, offs, csr, hn2, norms2);
    k_pull2<<<6250, 256, 0, stream>>>(hn2, norms2, offs, csr, beta, W2, b2, out);
  }
}

// Round 8
// 278.289 us; speedup vs baseline: 2.3593x; 2.3593x over previous
//
#include <hip/hip_runtime.h>
#include <hip/hip_fp16.h>
#include <math.h>

#define N_NODES 100000
#define N_EDGES 3200000
#define EPRIME  (N_EDGES + N_NODES)
#define NFEAT   512
#define HID     16
#define NCLS    10

#define NPB     256                            // nodes per bucket
#define NB      ((N_NODES + NPB - 1) / NPB)    // 391 buckets
#define CHUNK   4096                           // edges per partition chunk
#define NCH     ((EPRIME + CHUNK - 1) / CHUNK) // 806 chunks
#define CAPB    10240                          // fixed csr region per bucket (mean 8448 + ~20 sigma)
#define NGEMM   1024                           // gemm blocks inside k_gemm_csr

union U2 { unsigned int u; __half2 h; };
__device__ __forceinline__ float2 u2f(unsigned int v) {
  U2 t; t.u = v; return __half22float2(t.h);
}

// ---------------------------------------------------------------------------
// D1: partition each 4096-edge chunk into its OWN slot region, grouped by
// bucket, plus packed header hdr[c*NB+b] = (start<<16)|cnt.  Pure overwrite:
// no global atomics, no initialization required.
// ---------------------------------------------------------------------------
__global__ __launch_bounds__(256) void k_part2(const int* __restrict__ ei,
                                               unsigned int* __restrict__ slots,
                                               unsigned int* __restrict__ hdr) {
  __shared__ int sh_hist[NB];
  __shared__ int sh_start[NB];
  const int c = blockIdx.x, tid = threadIdx.x;

  for (int i = tid; i < NB; i += 256) sh_hist[i] = 0;
  __syncthreads();

  const int base = c * CHUNK;
  unsigned int pk[16];
  int bk[16], rk[16];
#pragma unroll
  for (int j = 0; j < 16; ++j) {
    int e = base + j * 256 + tid;
    bool valid = (e < EPRIME);
    int srcv = 0, d = 0;
    if (valid) {
      if (e < N_EDGES) { srcv = ei[e]; d = ei[N_EDGES + e]; }
      else             { srcv = d = e - N_EDGES; }
    }
    bk[j] = valid ? (d >> 8) : -1;
    pk[j] = (unsigned)srcv | ((unsigned)(d & 255) << 20);
    rk[j] = valid ? atomicAdd(&sh_hist[d >> 8], 1) : 0;
  }
  __syncthreads();

  // wave 0: exclusive scan of sh_hist[0..NB) into sh_start
  if (tid < 64) {
    int carry = 0;
    for (int b0 = 0; b0 < NB; b0 += 64) {
      const int idx = b0 + tid;
      const int v = (idx < NB) ? sh_hist[idx] : 0;
      int s = v;
#pragma unroll
      for (int d = 1; d < 64; d <<= 1) {
        int u = __shfl_up(s, d);
        if (tid >= d) s += u;
      }
      if (idx < NB) sh_start[idx] = s - v + carry;
      carry += __shfl(s, 63);
    }
  }
  __syncthreads();

  // coalesced header write (c-major)
  for (int b = tid; b < NB; b += 256)
    hdr[(size_t)c * NB + b] = ((unsigned)sh_start[b] << 16) | (unsigned)sh_hist[b];

  // scatter into this chunk's 16KB slot region (L2-local)
#pragma unroll
  for (int j = 0; j < 16; ++j)
    if (bk[j] >= 0)
      slots[(size_t)base + sh_start[bk[j]] + rk[j]] = pk[j];
}

// ---------------------------------------------------------------------------
// Per-bucket CSR finalize into fixed region [b*CAPB, b*CAPB+ne): two passes
// over this bucket's runs in the chunk-local slots (via headers).
// Writes soffs[node] (global start) and ecnt[node] (count).
// Zeroes the 16 entries past ne: pull_body over-reads up to 15 slots and
// the gap to CAPB is otherwise 0xAA poison (round-7 crash).
// ---------------------------------------------------------------------------
__device__ void csr_fin(int b, const unsigned int* __restrict__ slots,
                        const unsigned int* __restrict__ hdr,
                        unsigned int* __restrict__ csr,
                        unsigned int* __restrict__ soffs,
                        unsigned short* __restrict__ ecnt) {
  __shared__ int sh_cnt[NPB];
  __shared__ int sh_cnt2[NPB];
  __shared__ int sh_sc[NPB];
  __shared__ int sh_loffs[NPB];
  const int tid = threadIdx.x;

  sh_cnt[tid] = 0;
  sh_cnt2[tid] = 0;
  __syncthreads();

  // pass 1: per-local-node histogram
  for (int c = tid; c < NCH; c += 256) {
    const unsigned h = hdr[(size_t)c * NB + b];
    const int cnt = h & 0xFFFF, st = h >> 16;
    const unsigned int* p = slots + (size_t)c * CHUNK + st;
    for (int i = 0; i < cnt; ++i) atomicAdd(&sh_cnt[p[i] >> 20], 1);
  }
  __syncthreads();

  const int v = sh_cnt[tid];
  sh_sc[tid] = v;
  __syncthreads();
  for (int d = 1; d < NPB; d <<= 1) {
    int u = (tid >= d) ? sh_sc[tid - d] : 0;
    __syncthreads();
    sh_sc[tid] += u;
    __syncthreads();
  }
  const int excl = sh_sc[tid] - v;
  sh_loffs[tid] = excl;

  const int ne = sh_sc[NPB - 1];  // bucket total (max ~8.8k << CAPB-16)
  // zero the over-read pad just past the live region
  if (tid < 16) csr[(size_t)b * CAPB + ne + tid] = 0;

  const int node = b * NPB + tid;
  if (node < N_NODES) {
    soffs[node] = (unsigned)(b * CAPB + excl);
    ecnt[node]  = (unsigned short)v;
  }
  __syncthreads();

  // pass 2: scatter srcs into the bucket's csr region (~40KB, L2-local)
  for (int c = tid; c < NCH; c += 256) {
    const unsigned h = hdr[(size_t)c * NB + b];
    const int cnt = h & 0xFFFF, st = h >> 16;
    const unsigned int* p = slots + (size_t)c * CHUNK + st;
    for (int i = 0; i < cnt; ++i) {
      const unsigned pv = p[i];
      const int local = pv >> 20;
      const int r = atomicAdd(&sh_cnt2[local], 1);
      csr[(size_t)b * CAPB + sh_loffs[local] + r] = pv & 0xFFFFF;
    }
  }
}

// ---------------------------------------------------------------------------
// D2: blocks [0,NB) finalize csr; blocks [NB, NB+NGEMM) run the gemm:
// hn1 = fp16(normalize(relu(x @ W1 + b1))); norms1 = ||relu||.
// Independent data -> safe in one dispatch; csr blocks dispatch first.
// ---------------------------------------------------------------------------
__global__ __launch_bounds__(256) void k_gemm_csr(const float* __restrict__ x,
                                                  const float* __restrict__ W1,
                                                  const float* __restrict__ b1,
                                                  __half* __restrict__ hn1,
                                                  float* __restrict__ norms1,
                                                  const unsigned int* __restrict__ slots,
                                                  const unsigned int* __restrict__ hdr,
                                                  unsigned int* __restrict__ csr,
                                                  unsigned int* __restrict__ soffs,
                                                  unsigned short* __restrict__ ecnt) {
  if (blockIdx.x < NB) {
    csr_fin(blockIdx.x, slots, hdr, csr, soffs, ecnt);
    return;
  }

  const int lane = threadIdx.x & 63;
  const int wid  = (blockIdx.x - NB) * 4 + (threadIdx.x >> 6);
  const int nw   = NGEMM * 4;

  float4 w[8][4];
#pragma unroll
  for (int kk = 0; kk < 8; ++kk)
#pragma unroll
    for (int j = 0; j < 4; ++j)
      w[kk][j] = *reinterpret_cast<const float4*>(W1 + (lane * 8 + kk) * 16 + j * 4);

  const int outCol = (lane >> 2) & 15;
  const float bias = b1[outCol];

  const float4 z4 = make_float4(0.f, 0.f, 0.f, 0.f);
  float4 c0 = z4, c1 = z4, p0 = z4, p1 = z4, t0 = z4, t1 = z4;

  if (wid < N_NODES) {
    c0 = *reinterpret_cast<const float4*>(x + (size_t)wid * NFEAT + lane * 8);
    c1 = *reinterpret_cast<const float4*>(x + (size_t)wid * NFEAT + lane * 8 + 4);
  }
  if (wid + nw < N_NODES) {
    p0 = *reinterpret_cast<const float4*>(x + (size_t)(wid + nw) * NFEAT + lane * 8);
    p1 = *reinterpret_cast<const float4*>(x + (size_t)(wid + nw) * NFEAT + lane * 8 + 4);
  }

  for (int row = wid; row < N_NODES; row += nw) {
    const int r2 = row + 2 * nw;
    if (r2 < N_NODES) {
      t0 = *reinterpret_cast<const float4*>(x + (size_t)r2 * NFEAT + lane * 8);
      t1 = *reinterpret_cast<const float4*>(x + (size_t)r2 * NFEAT + lane * 8 + 4);
    }

    float xs[8] = {c0.x, c0.y, c0.z, c0.w, c1.x, c1.y, c1.z, c1.w};

    float acc[16];
#pragma unroll
    for (int j = 0; j < 16; ++j) acc[j] = 0.f;

#pragma unroll
    for (int kk = 0; kk < 8; ++kk) {
      const float xv = xs[kk];
#pragma unroll
      for (int j4 = 0; j4 < 4; ++j4) {
        acc[j4 * 4 + 0] = fmaf(xv, w[kk][j4].x, acc[j4 * 4 + 0]);
        acc[j4 * 4 + 1] = fmaf(xv, w[kk][j4].y, acc[j4 * 4 + 1]);
        acc[j4 * 4 + 2] = fmaf(xv, w[kk][j4].z, acc[j4 * 4 + 2]);
        acc[j4 * 4 + 3] = fmaf(xv, w[kk][j4].w, acc[j4 * 4 + 3]);
      }
    }

#pragma unroll
    for (int i = 0; i < 8; ++i) {
      float send = (lane & 32) ? acc[i] : acc[i + 8];
      float r = __shfl_xor(send, 32);
      acc[i] = ((lane & 32) ? acc[i + 8] : acc[i]) + r;
    }
#pragma unroll
    for (int i = 0; i < 4; ++i) {
      float send = (lane & 16) ? acc[i] : acc[i + 4];
      float r = __shfl_xor(send, 16);
      acc[i] = ((lane & 16) ? acc[i + 4] : acc[i]) + r;
    }
#pragma unroll
    for (int i = 0; i < 2; ++i) {
      float send = (lane & 8) ? acc[i] : acc[i + 2];
      float r = __shfl_xor(send, 8);
      acc[i] = ((lane & 8) ? acc[i + 2] : acc[i]) + r;
    }
    {
      float send = (lane & 4) ? acc[0] : acc[1];
      float r = __shfl_xor(send, 4);
      acc[0] = ((lane & 4) ? acc[1] : acc[0]) + r;
    }
    acc[0] += __shfl_xor(acc[0], 2);
    acc[0] += __shfl_xor(acc[0], 1);

    const float v = fmaxf(acc[0] + bias, 0.f);
    float ss = v * v;
    ss += __shfl_xor(ss, 4);
    ss += __shfl_xor(ss, 8);
    ss += __shfl_xor(ss, 16);
    ss += __shfl_xor(ss, 32);
    const float nrm = sqrtf(ss);
    const float vs = v / fmaxf(nrm, 1e-12f);

    const float wv = __shfl(vs, (lane & 15) * 4);
    if (lane < 16) hn1[(size_t)row * HID + lane] = __float2half_rn(wv);
    if (lane == 0) norms1[row] = nrm;

    c0 = p0; c1 = p1; p0 = t0; p1 = t1;
  }
}

// ---------------------------------------------------------------------------
// Pull-mode AGNN conv, one wave per dst node.  16 edge slots x 4 feature
// lanes; hn fp16 (L2-resident), fp32 accumulate.  FINAL=false: fuse next
// layer's normalize.  FINAL=true: fuse logits + log_softmax.
// Over-read past e (up to 15 slots) reads the zeroed pad -> src=0, t=0.
// ---------------------------------------------------------------------------
template <bool FINAL>
__device__ __forceinline__ void pull_body(const __half* __restrict__ hn,
                                          const float* __restrict__ norms,
                                          const unsigned int* __restrict__ soffs,
                                          const unsigned short* __restrict__ ecnt,
                                          const unsigned int* __restrict__ csr,
                                          float beta,
                                          __half* __restrict__ out_hn,
                                          float* __restrict__ out_norms,
                                          const float* __restrict__ W2,
                                          const float* __restrict__ b2,
                                          float* __restrict__ out) {
  const int node = blockIdx.x * 4 + (threadIdx.x >> 6);
  if (node >= N_NODES) return;
  const int lane = threadIdx.x & 63;
  const int q    = lane & 3;   // feature quad
  const int slot = lane >> 2;  // edge slot 0..15

  float w4x = 0.f, w4y = 0.f, w4z = 0.f, w4w = 0.f, b2v = 0.f;
  if (FINAL) {
    const int sc = (slot < NCLS) ? slot : 0;
    w4x = W2[(q * 4 + 0) * NCLS + sc];
    w4y = W2[(q * 4 + 1) * NCLS + sc];
    w4z = W2[(q * 4 + 2) * NCLS + sc];
    w4w = W2[(q * 4 + 3) * NCLS + sc];
    b2v = b2[sc];
  }

  const uint2 qraw = *reinterpret_cast<const uint2*>(hn + (size_t)node * HID + q * 4);
  const float2 qa = u2f(qraw.x), qb = u2f(qraw.y);
  const unsigned s = soffs[node];
  const unsigned e = s + ecnt[node];

  float den = 0.f;
  float ax = 0.f, ay = 0.f, az = 0.f, aw = 0.f;

  for (unsigned bi = s; bi < e; bi += 16) {
    const unsigned i = bi + slot;
    const int src = (int)csr[i];  // past-e reads hit the zero pad
    const uint2 r = *reinterpret_cast<const uint2*>(hn + (size_t)src * HID + q * 4);
    const float2 f0 = u2f(r.x), f1 = u2f(r.y);
    float pd = qa.x * f0.x + qa.y * f0.y + qb.x * f1.x + qb.y * f1.y;
    pd += __shfl_xor(pd, 1);
    pd += __shfl_xor(pd, 2);
    const float t = (i < e) ? __expf(beta * pd) : 0.f;
    den += t;
    const float wgt = t * norms[src];
    ax += wgt * f0.x; ay += wgt * f0.y; az += wgt * f1.x; aw += wgt * f1.y;
  }

#pragma unroll
  for (int m = 4; m <= 32; m <<= 1) {
    den += __shfl_xor(den, m);
    ax  += __shfl_xor(ax, m);
    ay  += __shfl_xor(ay, m);
    az  += __shfl_xor(az, m);
    aw  += __shfl_xor(aw, m);
  }
  const float inv = 1.0f / den;  // self-loop guarantees den > 0
  ax *= inv; ay *= inv; az *= inv; aw *= inv;

  if (!FINAL) {
    float ssn = ax * ax + ay * ay + az * az + aw * aw;
    ssn += __shfl_xor(ssn, 1);
    ssn += __shfl_xor(ssn, 2);
    const float nrm = sqrtf(ssn);
    const float ninv = 1.0f / fmaxf(nrm, 1e-12f);
    if (lane < 4) {
      U2 lo, hi;
      lo.h = __floats2half2_rn(ax * ninv, ay * ninv);
      hi.h = __floats2half2_rn(az * ninv, aw * ninv);
      *reinterpret_cast<uint2*>(out_hn + (size_t)node * HID + q * 4) =
          make_uint2(lo.u, hi.u);
      if (lane == 0) out_norms[node] = nrm;
    }
  } else {
    float part = ax * w4x + ay * w4y + az * w4z + aw * w4w;
    part += __shfl_xor(part, 1);
    part += __shfl_xor(part, 2);
    const float logit = part + b2v;  // valid on slots 0..9 (all q replicate)

    float lg[NCLS];
#pragma unroll
    for (int c = 0; c < NCLS; ++c) lg[c] = __shfl(logit, c * 4);
    float m = lg[0];
#pragma unroll
    for (int c = 1; c < NCLS; ++c) m = fmaxf(m, lg[c]);
    float se = 0.f;
#pragma unroll
    for (int c = 0; c < NCLS; ++c) se += __expf(lg[c] - m);
    const float ls = m + logf(se);

    const float myv = __shfl(logit, lane * 4);
    if (lane < NCLS) out[(size_t)node * NCLS + lane] = myv - ls;
  }
}

__global__ __launch_bounds__(256) void k_pull1(const __half* __restrict__ hn1,
                                               const float* __restrict__ norms1,
                                               const unsigned int* __restrict__ soffs,
                                               const unsigned short* __restrict__ ecnt,
                                               const unsigned int* __restrict__ csr,
                                               __half* __restrict__ hn2,
                                               float* __restrict__ norms2) {
  pull_body<false>(hn1, norms1, soffs, ecnt, csr, 1.0f, hn2, norms2,
                   nullptr, nullptr, nullptr);
}

__global__ __launch_bounds__(256) void k_pull2(const __half* __restrict__ hn2,
                                               const float* __restrict__ norms2,
                                               const unsigned int* __restrict__ soffs,
                                               const unsigned short* __restrict__ ecnt,
                                               const unsigned int* __restrict__ csr,
                                               const float* __restrict__ beta_ptr,
                                               const float* __restrict__ W2,
                                               const float* __restrict__ b2,
                                               float* __restrict__ out) {
  pull_body<true>(hn2, norms2, soffs, ecnt, csr, beta_ptr[0], nullptr, nullptr,
                  W2, b2, out);
}

// ---------------------------------------------------------------------------
extern "C" void kernel_launch(void* const* d_in, const int* in_sizes, int n_in,
                              void* d_out, int out_size, void* d_ws, size_t ws_size,
                              hipStream_t stream) {
  const float* x    = (const float*)d_in[0];
  const int*   ei   = (const int*)d_in[1];
  const float* W1   = (const float*)d_in[2];
  const float* b1   = (const float*)d_in[3];
  const float* beta = (const float*)d_in[4];
  const float* W2   = (const float*)d_in[5];
  const float* b2   = (const float*)d_in[6];
  float* out = (float*)d_out;

  // Workspace layout (~39 MB); every array 16B-aligned by construction.
  char* p = (char*)d_ws;
  __half* hn1 = (__half*)p;                 p += (size_t)N_NODES * HID * 2;
  float* norms1 = (float*)p;                p += (size_t)N_NODES * 4;
  __half* hn2 = (__half*)p;                 p += (size_t)N_NODES * HID * 2;
  float* norms2 = (float*)p;                p += (size_t)N_NODES * 4;
  unsigned int* soffs = (unsigned int*)p;   p += (size_t)N_NODES * 4;
  unsigned short* ecnt = (unsigned short*)p; p += (size_t)N_NODES * 2 + 64;
  unsigned int* csr = (unsigned int*)p;     p += ((size_t)NB * CAPB + 16) * 4;
  unsigned int* slots = (unsigned int*)p;   p += (size_t)NCH * CHUNK * 4;
  unsigned int* hdr = (unsigned int*)p;     // NCH*NB u32

  k_part2<<<NCH, 256, 0, stream>>>(ei, slots, hdr);
  k_gemm_csr<<<NB + NGEMM, 256, 0, stream>>>(x, W1, b1, hn1, norms1,
                                             slots, hdr, csr, soffs, ecnt);
  const int nblW = (N_NODES + 3) / 4;  // wave per node, 4 waves/block
  k_pull1<<<nblW, 256, 0, stream>>>(hn1, norms1, soffs, ecnt, csr, hn2, norms2);
  k_pull2<<<nblW, 256, 0, stream>>>(hn2, norms2, soffs, ecnt, csr, beta, W2, b2, out);
}